// Round 6
// baseline (6690.754 us; speedup 1.0000x reference)
//
#include <hip/hip_runtime.h>
#include <math.h>

#define NB 256   // batch
#define NT 512   // time steps
#define NF 65    // features
#define NH 512   // hidden
#define NCL 8    // clusters == physical XCDs
#define BPC 32   // blocks per cluster
#define BCL 32   // batch rows per cluster
#define XMS 136  // padded xm row stride (f16)
#define TS  272  // exch tile: 16 rows x 17 f32 (padded vs bank conflicts)

typedef __attribute__((ext_vector_type(8))) _Float16 f16x8;
typedef __attribute__((ext_vector_type(4))) float   f32x4;

__device__ __align__(16) int      g_claim[NCL];
__device__ __align__(16) int      g_flags[NCL][BPC];
__device__ __align__(16) _Float16 g_h1[NCL*2*BCL*NH];      // [cl][parity][32][512]
__device__ __align__(16) _Float16 g_h2[NCL*2*BCL*NH];
__device__ __align__(16) float    g_stats[2][NCL*BCL*BPC*2]; // t-parity double buffer
__device__ __align__(16) float    g_pool[NB*NH];
__device__ __align__(16) float    g_Wt[NH*(NH/2)];
__device__ __align__(16) _Float16 g_xm[(size_t)NB*NT*XMS + 256];

__device__ __forceinline__ float sigm(float v)  { return 1.f/(1.f+__expf(-v)); }
__device__ __forceinline__ float tanh_(float v) { return 1.f-2.f/(1.f+__expf(2.f*v)); }

// PROVEN (r4/r5) coherence pair: agent-scope relaxed atomic stores (write through
// to the MALL) + sc0 sc1 loads (bypass L1 AND the possibly-stale L2 copy).
__device__ __forceinline__ void st_h16(_Float16* p, float v) {
  unsigned short u = __builtin_bit_cast(unsigned short, (_Float16)v);
  __hip_atomic_store((unsigned short*)p, u, __ATOMIC_RELAXED, __HIP_MEMORY_SCOPE_AGENT);
}
__device__ __forceinline__ void st_f32(float* p, float v) {
  __hip_atomic_store(p, v, __ATOMIC_RELAXED, __HIP_MEMORY_SCOPE_AGENT);
}

#define GLDC(D,P,O) asm volatile("global_load_dwordx4 %0, %1, off offset:" #O " sc0 sc1" : "=&v"(D) : "v"(P));
#define GLDP(D,P,O) asm volatile("global_load_dwordx4 %0, %1, off offset:" #O : "=&v"(D) : "v"(P));
#define LDH16(AF,AP)                                                        \
  GLDC(AF[0],AP,0)    GLDC(AF[1],AP,64)   GLDC(AF[2],AP,128)  GLDC(AF[3],AP,192)  \
  GLDC(AF[4],AP,256)  GLDC(AF[5],AP,320)  GLDC(AF[6],AP,384)  GLDC(AF[7],AP,448)  \
  GLDC(AF[8],AP,512)  GLDC(AF[9],AP,576)  GLDC(AF[10],AP,640) GLDC(AF[11],AP,704) \
  GLDC(AF[12],AP,768) GLDC(AF[13],AP,832) GLDC(AF[14],AP,896) GLDC(AF[15],AP,960)
#define VMF0()                                          \
  asm volatile("s_waitcnt vmcnt(0)" ::: "memory");      \
  __builtin_amdgcn_sched_barrier(0);
#define MF(a,b,c) __builtin_amdgcn_mfma_f32_16x16x32_f16(a,b,c,0,0,0)
#define BF(W,g,c) (*(const f16x8*)((W) + (((g)*16+(c))*64 + l)*8))

__global__ void init_kernel(const float* __restrict__ Wp,
                            const float* __restrict__ x, const int* __restrict__ mask) {
  long i0 = (long)blockIdx.x * blockDim.x + threadIdx.x;
  long n  = (long)gridDim.x * blockDim.x;
  for (long i = i0; i < NCL; i += n) g_claim[i] = 0;
  for (long i = i0; i < NCL*BPC; i += n) ((int*)g_flags)[i] = 0;
  for (long i = i0; i < NCL*2*BCL*NH; i += n) { g_h1[i]=(_Float16)0.f; g_h2[i]=(_Float16)0.f; }
  for (long i = i0; i < NH*(NH/2); i += n) g_Wt[i] = Wp[(i & 255)*NH + (i >> 8)];
  const long total = (long)NB*NT*XMS;
  for (long i = i0; i < total + 256; i += n) {
    if (i >= total) { g_xm[i] = (_Float16)0.f; continue; }
    long row = i / XMS; int col = (int)(i % XMS);
    float v = 0.f;
    if (col < NF)          v = x[row*NF + col];
    else if (col < 2*NF)   v = (float)mask[row*NF + col - NF];
    g_xm[i] = (_Float16)v;
  }
}

// Layer-skewed persistent GRU: superstep s computes h1(s) (layer0, s<NT) and
// h2(s-1) (layer1, s>=1). Both consume only h1(s-1)/h2(s-2)/xm(s), all
// published by ONE cluster barrier per superstep. 1 fence + 1 barrier +
// 3 syncthreads per superstep (r5 had 2 fences + 2 barriers + 6 syncs).
// Waves: p = w>>1 (m-tile), hf = w&1.
//   hf0: hh0_r+ih0_r, ih0_n, L1 r (ih1+hh1), L1 z  -> all 4 accs stay in regs,
//        then does gate math + LN partials (90 MFMA).
//   hf1: hh0_z+ih0_z, hh0_n, ih1_n, hh1_n -> 4 LDS exch tiles (69 MFMA);
//        w1 polls the cluster barrier.
__global__ __launch_bounds__(256, 1) void gru_main(
    const float* __restrict__ Wih0, const float* __restrict__ Whh0,
    const float* __restrict__ bih0, const float* __restrict__ bhh0,
    const float* __restrict__ Wih1, const float* __restrict__ Whh1,
    const float* __restrict__ bih1, const float* __restrict__ bhh1,
    const float* __restrict__ lng,  const float* __restrict__ lnb) {
  extern __shared__ char lds[];
  _Float16* wHH0 = (_Float16*)lds;
  _Float16* wIH1 = (_Float16*)(lds + 49152);
  _Float16* wHH1 = (_Float16*)(lds + 98304);
  float*    exch = (float*)(lds + 147456);   // 8 tiles * 272 f32 = 8704 B

  const int tid = threadIdx.x;
  const int w = tid >> 6, l = tid & 63, l15 = l & 15, lgp = l >> 4;
  const int p = w >> 1, hf = w & 1;

  if (tid == 0) {
    unsigned xcc;
    asm volatile("s_getreg_b32 %0, hwreg(HW_REG_XCC_ID)" : "=s"(xcc));
    int c = (int)(xcc & 7u);
    int qq = __hip_atomic_fetch_add(&g_claim[c], 1, __ATOMIC_RELAXED, __HIP_MEMORY_SCOPE_AGENT);
    ((int*)exch)[0] = c; ((int*)exch)[1] = qq & 31;
  }
  __syncthreads();
  const int cl = ((int*)exch)[0], q = ((int*)exch)[1];
  const int j0 = q * 16;

  // Pack weight slices into MFMA B-fragment order (r5-proven).
  for (int e = tid; e < 3*16*NH; e += 256) {
    int k = e & 511, ru = e >> 9;
    int g = ru >> 4, u = ru & 15;
    int src = (g*NH + j0 + u)*NH + k;
    int dst = ((g*16 + (k>>5))*64 + ((((k>>3)&3)<<4) | u))*8 + (k&7);
    wHH0[dst] = (_Float16)Whh0[src];
    wIH1[dst] = (_Float16)Wih1[src];
    wHH1[dst] = (_Float16)Whh1[src];
  }

  // ih0 weight frags: hf0 -> [0..4]=r, [5..9]=n ; hf1 -> [0..4]=z
  f16x8 wfA[10];
  #pragma unroll
  for (int c = 0; c < 5; c++) {
    #pragma unroll
    for (int j = 0; j < 8; j++) {
      int k = c*32 + lgp*8 + j;
      float v0 = (k < 130) ? Wih0[((hf ? 1 : 0)*NH + j0 + l15)*130 + k] : 0.f;
      wfA[c][j] = (_Float16)v0;
      float v1 = (!hf && k < 130) ? Wih0[(2*NH + j0 + l15)*130 + k] : 0.f;
      wfA[5+c][j] = (_Float16)v1;
    }
  }

  const int ucol = j0 + l15;
  const float cbr0 = bih0[ucol] + bhh0[ucol];
  const float cbz0 = bih0[NH+ucol] + bhh0[NH+ucol];
  const float bin0 = bih0[2*NH+ucol], bhn0 = bhh0[2*NH+ucol];
  const float cbr1 = bih1[ucol] + bhh1[ucol];
  const float cbz1 = bih1[NH+ucol] + bhh1[NH+ucol];
  const float bin1 = bih1[2*NH+ucol], bhn1 = bhh1[2*NH+ucol];

  const int arow0 = (p*16 + l15)*NH + lgp*8;
  const int sOff  = ((cl*BCL + p*16 + l15)*BPC + lgp*8)*2;
  const _Float16* xptr = g_xm + ((long)(cl*BCL + p*16 + l15)*NT)*XMS + lgp*8;

  float h1loc[4]={0,0,0,0}, h2loc[4]={0,0,0,0};
  float A1[4]={0,0,0,0}, A0[4]={0,0,0,0}, lastc[4]={0,0,0,0};
  f16x8 af1[16], af2[16], xmf[5];
  f32x4 sts0, sts1, sts2, sts3;
  const f32x4 z4v = {0.f,0.f,0.f,0.f};

  auto stTile = [&](int idx, f32x4 a) {
    float* et = exch + idx*TS;
    #pragma unroll
    for (int r = 0; r < 4; r++) et[(lgp*4+r)*17 + l15] = a[r];
  };
  auto lnFinish = [&](bool last) {
    float s  = (sts0[0]+sts1[0]) + (sts2[0]+sts3[0]) + (sts0[2]+sts1[2]) + (sts2[2]+sts3[2]);
    float ss = (sts0[1]+sts1[1]) + (sts2[1]+sts3[1]) + (sts0[3]+sts1[3]) + (sts2[3]+sts3[3]);
    s += __shfl_xor(s,16); ss += __shfl_xor(ss,16);
    s += __shfl_xor(s,32); ss += __shfl_xor(ss,32);
    #pragma unroll
    for (int r = 0; r < 4; r++) {
      float S = __shfl(s, lgp*4+r), SS = __shfl(ss, lgp*4+r);
      float mu = S*(1.f/NH), var = SS*(1.f/NH) - mu*mu;
      float inv = rsqrtf(var + 1e-5f);
      A1[r] += h2loc[r]*inv; A0[r] += mu*inv;
      if (last) lastc[r] = (h2loc[r]-mu)*inv;
    }
  };

  __syncthreads();   // weight pack visible (also orders cl/q read vs tile use)

  for (int s = 0; s <= NT; ++s) {
    const _Float16* h1r = g_h1 + (cl*2 + ((s+1)&1))*BCL*NH;  // h1(s-1)
    _Float16*       h1w = g_h1 + (cl*2 + (s&1))*BCL*NH;      // h1(s)
    const _Float16* h2r = g_h2 + (cl*2 + (s&1))*BCL*NH;      // h2(s-2)
    _Float16*       h2w = g_h2 + (cl*2 + ((s+1)&1))*BCL*NH;  // h2(s-1)

    // ---- all loads for this superstep, ONE fence ----
    { const _Float16* ap = h1r + arow0; LDH16(af1, ap) }
    if (s >= 1) { const _Float16* ap = h2r + arow0; LDH16(af2, ap) }
    if (s < NT) {
      GLDP(xmf[0],xptr,0) GLDP(xmf[1],xptr,64) GLDP(xmf[2],xptr,128)
      GLDP(xmf[3],xptr,192) GLDP(xmf[4],xptr,256)
    }
    if (hf == 0 && s >= 2) {   // stats(t=s-2), parity (s-2)&1 = s&1
      const float* sp = g_stats[s&1] + sOff;
      GLDC(sts0,sp,0) GLDC(sts1,sp,16) GLDC(sts2,sp,32) GLDC(sts3,sp,48)
    }
    VMF0()

    // ---- MFMA block ----
    f32x4 acc0=z4v, acc1=z4v, acc2=z4v, acc3=z4v;
    if (hf == 0) {
      if (s < NT) {
        #pragma unroll
        for (int c = 0; c < 16; c++) acc0 = MF(af1[c], BF(wHH0,0,c), acc0);
        #pragma unroll
        for (int c = 0; c < 5; c++) {
          acc0 = MF(xmf[c], wfA[c],   acc0);   // + ih0_r
          acc1 = MF(xmf[c], wfA[5+c], acc1);   // ih0_n
        }
      }
      if (s >= 1) {
        #pragma unroll
        for (int c = 0; c < 16; c++) {
          acc2 = MF(af1[c], BF(wIH1,0,c), acc2);   // L1 r: ih part
          acc3 = MF(af1[c], BF(wIH1,1,c), acc3);   // L1 z: ih part
          acc2 = MF(af2[c], BF(wHH1,0,c), acc2);   // L1 r: hh part
          acc3 = MF(af2[c], BF(wHH1,1,c), acc3);   // L1 z: hh part
        }
      }
    } else {
      if (s < NT) {
        #pragma unroll
        for (int c = 0; c < 16; c++) {
          acc0 = MF(af1[c], BF(wHH0,1,c), acc0);   // hh0_z
          acc1 = MF(af1[c], BF(wHH0,2,c), acc1);   // hh0_n
        }
        #pragma unroll
        for (int c = 0; c < 5; c++) acc0 = MF(xmf[c], wfA[c], acc0);  // + ih0_z
        stTile(p*4+0, acc0); stTile(p*4+1, acc1);
      }
      if (s >= 1) {
        #pragma unroll
        for (int c = 0; c < 16; c++) {
          acc2 = MF(af1[c], BF(wIH1,2,c), acc2);   // ih1_n
          acc3 = MF(af2[c], BF(wHH1,2,c), acc3);   // hh1_n
        }
        stTile(p*4+2, acc2); stTile(p*4+3, acc3);
      }
    }
    if (hf == 0 && s >= 2) lnFinish(false);   // t=s-2, uses h2loc BEFORE update
    __syncthreads();

    // ---- gate math (hf0 waves) ----
    if (hf == 0) {
      const float* ez   = exch + (p*4+0)*TS;
      const float* en0h = exch + (p*4+1)*TS;
      const float* en1i = exch + (p*4+2)*TS;
      const float* en1h = exch + (p*4+3)*TS;
      #pragma unroll
      for (int r = 0; r < 4; r++) {
        int ro = (lgp*4+r)*17 + l15;
        int row = p*16 + lgp*4 + r;
        if (s < NT) {
          float rg = sigm(acc0[r] + cbr0);
          float zg = sigm(ez[ro] + cbz0);
          float ng = tanh_(acc1[r] + bin0 + rg*(en0h[ro] + bhn0));
          float hn = (1.f-zg)*ng + zg*h1loc[r];
          h1loc[r] = hn;
          st_h16(&h1w[row*NH + ucol], hn);
        }
        if (s >= 1) {
          float rg = sigm(acc2[r] + cbr1);
          float zg = sigm(acc3[r] + cbz1);
          float ng = tanh_(en1i[ro] + bin1 + rg*(en1h[ro] + bhn1));
          float hn = (1.f-zg)*ng + zg*h2loc[r];
          h2loc[r] = hn;
          st_h16(&h2w[row*NH + ucol], hn);
          float v = hn, v2 = hn*hn;
          v += __shfl_xor(v,1); v2 += __shfl_xor(v2,1);
          v += __shfl_xor(v,2); v2 += __shfl_xor(v2,2);
          v += __shfl_xor(v,4); v2 += __shfl_xor(v2,4);
          v += __shfl_xor(v,8); v2 += __shfl_xor(v2,8);
          if (l15 == 0) {   // stats(t=s-1) -> parity (s-1)&1 = (s+1)&1
            float* dp = g_stats[(s+1)&1] + ((cl*BCL + row)*BPC + q)*2;
            st_f32(&dp[0], v); st_f32(&dp[1], v2);
          }
        }
      }
    }
    __syncthreads();   // each wave drains its agent stores (vmcnt0) before barrier
    if (tid == 0)
      __hip_atomic_store(&g_flags[cl][q], s+1, __ATOMIC_RELAXED, __HIP_MEMORY_SCOPE_AGENT);
    if (w == 1) {
      for (;;) {
        int v = (l < BPC) ? __hip_atomic_load(&g_flags[cl][l], __ATOMIC_RELAXED,
                                              __HIP_MEMORY_SCOPE_AGENT)
                          : (s+1);
        if (__all(v >= s+1)) break;
        __builtin_amdgcn_s_sleep(1);
      }
    }
    __syncthreads();
    xptr += XMS;
  }

  // final LN (t = NT-1, stats parity 1) + pooled write
  if (hf == 0) {
    const float* sp = g_stats[1] + sOff;
    GLDC(sts0,sp,0) GLDC(sts1,sp,16) GLDC(sts2,sp,32) GLDC(sts3,sp,48)
    VMF0()
    lnFinish(true);
    float gg = lng[ucol], bb = lnb[ucol];
    #pragma unroll
    for (int r = 0; r < 4; r++) {
      float v = gg*(lastc[r] + (A1[r]-A0[r])*(1.f/NT)) + 2.f*bb;
      g_pool[(cl*BCL + p*16 + lgp*4 + r)*NH + ucol] = v;
    }
  }
}

__global__ __launch_bounds__(256) void proj_kernel(const float* __restrict__ bp,
                                                   float* __restrict__ out) {
  __shared__ float pr[NH];
  int b = blockIdx.x, o = threadIdx.x;
  pr[o] = g_pool[b*NH + o];
  pr[o+256] = g_pool[b*NH + 256 + o];
  __syncthreads();
  float acc = bp[o];
  #pragma unroll 8
  for (int u = 0; u < NH; ++u) acc = fmaf(pr[u], g_Wt[u*256 + o], acc);
  out[b*256 + o] = 0.5f*acc*(1.f + erff(acc*0.70710678118654752f));
}

extern "C" void kernel_launch(void* const* d_in, const int* in_sizes, int n_in,
                              void* d_out, int out_size, void* d_ws, size_t ws_size,
                              hipStream_t stream) {
  const float* x    = (const float*)d_in[0];
  const int*   mask = (const int*)d_in[1];
  const float* Wih0 = (const float*)d_in[2];
  const float* Whh0 = (const float*)d_in[3];
  const float* bih0 = (const float*)d_in[4];
  const float* bhh0 = (const float*)d_in[5];
  const float* Wih1 = (const float*)d_in[6];
  const float* Whh1 = (const float*)d_in[7];
  const float* bih1 = (const float*)d_in[8];
  const float* bhh1 = (const float*)d_in[9];
  const float* lng  = (const float*)d_in[10];
  const float* lnb  = (const float*)d_in[11];
  const float* Wp   = (const float*)d_in[12];
  const float* bp   = (const float*)d_in[13];
  float* out = (float*)d_out;
  (void)in_sizes; (void)n_in; (void)out_size; (void)d_ws; (void)ws_size;

  hipFuncSetAttribute(reinterpret_cast<const void*>(gru_main),
                      hipFuncAttributeMaxDynamicSharedMemorySize, 156160);

  hipLaunchKernelGGL(init_kernel, dim3(2048), dim3(256), 0, stream, Wp, x, mask);
  hipLaunchKernelGGL(gru_main, dim3(256), dim3(256), 156160, stream,
                     Wih0, Whh0, bih0, bhh0, Wih1, Whh1, bih1, bhh1, lng, lnb);
  hipLaunchKernelGGL(proj_kernel, dim3(NB), dim3(256), 0, stream, bp, out);
}

// Round 7
// 5018.628 us; speedup vs baseline: 1.3332x; 1.3332x over previous
//
#include <hip/hip_runtime.h>
#include <math.h>

#define NB 256   // batch
#define NT 512   // time steps
#define NF 65    // features
#define NH 512   // hidden
#define NCL 8    // clusters == physical XCDs
#define BPC 32   // blocks per cluster
#define BCL 32   // batch rows per cluster
#define XMS 136  // padded xm row stride (f16)

typedef __attribute__((ext_vector_type(8))) _Float16 f16x8;
typedef __attribute__((ext_vector_type(4))) float   f32x4;

__device__ __align__(16) int      g_claim[NCL];
__device__ __align__(16) int      g_flags[NCL][BPC];
__device__ __align__(16) _Float16 g_h1[NCL*2*BCL*NH];        // [cl][parity][32][512]
__device__ __align__(16) _Float16 g_h2[NCL*2*BCL*NH];
__device__ __align__(16) float    g_stats[2][NCL*BCL*BPC*2]; // t-parity double buffer
__device__ __align__(16) float    g_pool[NB*NH];
__device__ __align__(16) float    g_Wt[NH*(NH/2)];
__device__ __align__(16) _Float16 g_xm[(size_t)NB*NT*XMS + 256];

__device__ __forceinline__ float sigm(float v)  { return 1.f/(1.f+__expf(-v)); }
__device__ __forceinline__ float tanh_(float v) { return 1.f-2.f/(1.f+__expf(2.f*v)); }

// PROVEN (r4-r6) coherence pair: agent-scope relaxed atomic stores (write through
// to the MALL) + sc0 sc1 loads (bypass L1 and stale L2 copies).
__device__ __forceinline__ void st_h16(_Float16* p, float v) {
  unsigned short u = __builtin_bit_cast(unsigned short, (_Float16)v);
  __hip_atomic_store((unsigned short*)p, u, __ATOMIC_RELAXED, __HIP_MEMORY_SCOPE_AGENT);
}
__device__ __forceinline__ void st_f32(float* p, float v) {
  __hip_atomic_store(p, v, __ATOMIC_RELAXED, __HIP_MEMORY_SCOPE_AGENT);
}

#define GLDC(D,P,O) asm volatile("global_load_dwordx4 %0, %1, off offset:" #O " sc0 sc1" : "=&v"(D) : "v"(P));
#define GLDP(D,P,O) asm volatile("global_load_dwordx4 %0, %1, off offset:" #O : "=&v"(D) : "v"(P));
#define LDH16(AF,AP)                                                        \
  GLDC(AF[0],AP,0)    GLDC(AF[1],AP,64)   GLDC(AF[2],AP,128)  GLDC(AF[3],AP,192)  \
  GLDC(AF[4],AP,256)  GLDC(AF[5],AP,320)  GLDC(AF[6],AP,384)  GLDC(AF[7],AP,448)  \
  GLDC(AF[8],AP,512)  GLDC(AF[9],AP,576)  GLDC(AF[10],AP,640) GLDC(AF[11],AP,704) \
  GLDC(AF[12],AP,768) GLDC(AF[13],AP,832) GLDC(AF[14],AP,896) GLDC(AF[15],AP,960)
#define VMF0()                                          \
  asm volatile("s_waitcnt vmcnt(0)" ::: "memory");      \
  __builtin_amdgcn_sched_barrier(0);
#define MF(a,b,c) __builtin_amdgcn_mfma_f32_16x16x32_f16(a,b,c,0,0,0)
#define BF(W,g,c) (*(const f16x8*)((W) + (((g)*16+(c))*64 + l)*8))
#define BI0(g,c)  (*(const f16x8*)(wIH0 + (((g)*5+(c))*64 + l)*8))

__global__ void init_kernel(const float* __restrict__ Wp,
                            const float* __restrict__ x, const int* __restrict__ mask) {
  long i0 = (long)blockIdx.x * blockDim.x + threadIdx.x;
  long n  = (long)gridDim.x * blockDim.x;
  for (long i = i0; i < NCL; i += n) g_claim[i] = 0;
  for (long i = i0; i < NCL*BPC; i += n) ((int*)g_flags)[i] = 0;
  for (long i = i0; i < NCL*2*BCL*NH; i += n) { g_h1[i]=(_Float16)0.f; g_h2[i]=(_Float16)0.f; }
  for (long i = i0; i < NH*(NH/2); i += n) g_Wt[i] = Wp[(i & 255)*NH + (i >> 8)];
  const long total = (long)NB*NT*XMS;
  for (long i = i0; i < total + 256; i += n) {
    if (i >= total) { g_xm[i] = (_Float16)0.f; continue; }
    long row = i / XMS; int col = (int)(i % XMS);
    float v = 0.f;
    if (col < NF)          v = x[row*NF + col];
    else if (col < 2*NF)   v = (float)mask[row*NF + col - NF];
    g_xm[i] = (_Float16)v;
  }
}

// Layer-specialized superstep GRU. Superstep s: w0/w2 (lay=0, m-tiles 0/1)
// compute h1(s); w1/w3 (lay=1) compute h2(s-1). Each wave does ALL 3 gates of
// its (layer, m-tile): MFMA C-layout == gate-math layout -> gate math fully
// in-register, no LDS exchange, all waves' VALU tails run in parallel on their
// own SIMDs. Per superstep: 1 load fence + 1 cluster barrier + 2 syncthreads.
__global__ __launch_bounds__(256, 1) void gru_main(
    const float* __restrict__ Wih0, const float* __restrict__ Whh0,
    const float* __restrict__ bih0, const float* __restrict__ bhh0,
    const float* __restrict__ Wih1, const float* __restrict__ Whh1,
    const float* __restrict__ bih1, const float* __restrict__ bhh1,
    const float* __restrict__ lng,  const float* __restrict__ lnb) {
  extern __shared__ char lds[];
  _Float16* wHH0 = (_Float16*)lds;              // 48KB  (lay0)
  _Float16* wIH1 = (_Float16*)(lds + 49152);    // 48KB  (lay1)
  _Float16* wHH1 = (_Float16*)(lds + 98304);    // 48KB  (lay1)
  _Float16* wIH0 = (_Float16*)(lds + 147456);   // 15KB  (lay0, K=160 padded)

  const int tid = threadIdx.x;
  const int w = tid >> 6, l = tid & 63, l15 = l & 15, lgp = l >> 4;
  const int p = w >> 1, lay = w & 1;

  int* bcast = (int*)lds;   // overlaps wHH0; consumed before pack writes
  if (tid == 0) {
    unsigned xcc;
    asm volatile("s_getreg_b32 %0, hwreg(HW_REG_XCC_ID)" : "=s"(xcc));
    int c = (int)(xcc & 7u);
    int qq = __hip_atomic_fetch_add(&g_claim[c], 1, __ATOMIC_RELAXED, __HIP_MEMORY_SCOPE_AGENT);
    bcast[0] = c; bcast[1] = qq & 31;
  }
  __syncthreads();
  const int cl = bcast[0], q = bcast[1];
  const int j0 = q * 16;
  __syncthreads();   // cl/q read before pack overwrites lds[0..]

  // K=512 weight slices -> MFMA B-fragment order (r5/r6-proven mapping)
  for (int e = tid; e < 3*16*NH; e += 256) {
    int k = e & 511, ru = e >> 9;
    int g = ru >> 4, u = ru & 15;
    int src = (g*NH + j0 + u)*NH + k;
    int dst = ((g*16 + (k>>5))*64 + ((((k>>3)&3)<<4) | u))*8 + (k&7);
    wHH0[dst] = (_Float16)Whh0[src];
    wIH1[dst] = (_Float16)Wih1[src];
    wHH1[dst] = (_Float16)Whh1[src];
  }
  // ih0 (K=130 -> 160 padded) in the same frag order
  for (int e = tid; e < 3*16*160; e += 256) {
    int k = e % 160, ru = e / 160;
    int g = ru >> 4, u = ru & 15;
    float v = (k < 130) ? Wih0[(g*NH + j0 + u)*130 + k] : 0.f;
    int dst = ((g*5 + (k>>5))*64 + ((((k>>3)&3)<<4) | u))*8 + (k&7);
    wIH0[dst] = (_Float16)v;
  }

  const int ucol = j0 + l15;
  const float cbr = lay ? bih1[ucol]+bhh1[ucol]         : bih0[ucol]+bhh0[ucol];
  const float cbz = lay ? bih1[NH+ucol]+bhh1[NH+ucol]   : bih0[NH+ucol]+bhh0[NH+ucol];
  const float bin = lay ? bih1[2*NH+ucol]               : bih0[2*NH+ucol];
  const float bhn = lay ? bhh1[2*NH+ucol]               : bhh0[2*NH+ucol];

  const int arow0 = (p*16 + l15)*NH + lgp*8;
  const int sOff  = ((cl*BCL + p*16 + l15)*BPC + lgp*8)*2;
  const _Float16* xptr = g_xm + ((long)(cl*BCL + p*16 + l15)*NT)*XMS + lgp*8;

  float hloc[4] = {0,0,0,0};                 // h1loc (lay0) / h2loc (lay1)
  float A1[4]={0,0,0,0}, A0[4]={0,0,0,0}, lastc[4]={0,0,0,0};
  f16x8 af1[16], ag2[16], xmf[5];
  f32x4 sts0, sts1, sts2, sts3;
  const f32x4 z4v = {0.f,0.f,0.f,0.f};

  auto lnFinish = [&](bool last) {   // lay1 waves; uses hloc BEFORE gate-math update
    float s  = (sts0[0]+sts1[0]) + (sts2[0]+sts3[0]) + (sts0[2]+sts1[2]) + (sts2[2]+sts3[2]);
    float ss = (sts0[1]+sts1[1]) + (sts2[1]+sts3[1]) + (sts0[3]+sts1[3]) + (sts2[3]+sts3[3]);
    s += __shfl_xor(s,16); ss += __shfl_xor(ss,16);
    s += __shfl_xor(s,32); ss += __shfl_xor(ss,32);
    #pragma unroll
    for (int r = 0; r < 4; r++) {
      float S = __shfl(s, lgp*4+r), SS = __shfl(ss, lgp*4+r);
      float mu = S*(1.f/NH), var = SS*(1.f/NH) - mu*mu;
      float inv = rsqrtf(var + 1e-5f);
      A1[r] += hloc[r]*inv; A0[r] += mu*inv;
      if (last) lastc[r] = (hloc[r]-mu)*inv;
    }
  };

  __syncthreads();   // weight packs visible

  for (int s = 0; s <= NT; ++s) {
    const _Float16* h1r = g_h1 + (cl*2 + ((s+1)&1))*BCL*NH;  // h1(s-1)
    _Float16*       h1w = g_h1 + (cl*2 + (s&1))*BCL*NH;      // h1(s)
    const _Float16* h2r = g_h2 + (cl*2 + (s&1))*BCL*NH;      // h2(s-2)
    _Float16*       h2w = g_h2 + (cl*2 + ((s+1)&1))*BCL*NH;  // h2(s-1)
    const bool act = lay ? (s >= 1) : (s < NT);

    // ---- per-wave loads, one fence ----
    if (lay == 0) {
      if (act) {
        const _Float16* ap = h1r + arow0; LDH16(af1, ap)
        GLDP(xmf[0],xptr,0) GLDP(xmf[1],xptr,64) GLDP(xmf[2],xptr,128)
        GLDP(xmf[3],xptr,192) GLDP(xmf[4],xptr,256)
      }
    } else {
      if (act) {
        const _Float16* ap = h1r + arow0; LDH16(af1, ap)   // ih1 operand h1(s-1)
        const _Float16* aq = h2r + arow0; LDH16(ag2, aq)   // hh1 operand h2(s-2)
      }
      if (s >= 2) {   // stats(t=s-2), parity (s-2)&1 = s&1
        const float* sp = g_stats[s&1] + sOff;
        GLDC(sts0,sp,0) GLDC(sts1,sp,16) GLDC(sts2,sp,32) GLDC(sts3,sp,48)
      }
    }
    VMF0()

    // ---- MFMA: all 3 gates in-register (R/Z combined i+h; N split i,h) ----
    f32x4 aR=z4v, aZ=z4v, aNi=z4v, aNh=z4v;
    if (act) {
      if (lay == 0) {
        #pragma unroll
        for (int c = 0; c < 16; c++) {
          aR  = MF(af1[c], BF(wHH0,0,c), aR);
          aZ  = MF(af1[c], BF(wHH0,1,c), aZ);
          aNh = MF(af1[c], BF(wHH0,2,c), aNh);
        }
        #pragma unroll
        for (int c = 0; c < 5; c++) {
          aR  = MF(xmf[c], BI0(0,c), aR);
          aZ  = MF(xmf[c], BI0(1,c), aZ);
          aNi = MF(xmf[c], BI0(2,c), aNi);
        }
      } else {
        #pragma unroll
        for (int c = 0; c < 16; c++) {
          aR  = MF(af1[c], BF(wIH1,0,c), aR);
          aZ  = MF(af1[c], BF(wIH1,1,c), aZ);
          aNi = MF(af1[c], BF(wIH1,2,c), aNi);
          aR  = MF(ag2[c], BF(wHH1,0,c), aR);
          aZ  = MF(ag2[c], BF(wHH1,1,c), aZ);
          aNh = MF(ag2[c], BF(wHH1,2,c), aNh);
        }
      }
    }
    if (lay == 1 && s >= 2) lnFinish(false);   // t=s-2, hloc still h2(s-2)

    // ---- gate math, in-register, parallel across waves ----
    if (act) {
      _Float16* hw = lay ? h2w : h1w;
      #pragma unroll
      for (int r = 0; r < 4; r++) {
        int row = p*16 + lgp*4 + r;
        float rg = sigm(aR[r] + cbr);
        float zg = sigm(aZ[r] + cbz);
        float ng = tanh_(aNi[r] + bin + rg*(aNh[r] + bhn));
        float hn = (1.f-zg)*ng + zg*hloc[r];
        hloc[r] = hn;
        st_h16(&hw[row*NH + ucol], hn);
        if (lay == 1) {
          float v = hn, v2 = hn*hn;
          v += __shfl_xor(v,1); v2 += __shfl_xor(v2,1);
          v += __shfl_xor(v,2); v2 += __shfl_xor(v2,2);
          v += __shfl_xor(v,4); v2 += __shfl_xor(v2,4);
          v += __shfl_xor(v,8); v2 += __shfl_xor(v2,8);
          if (l15 == 0) {   // stats(t=s-1) -> parity (s-1)&1 = (s+1)&1
            float* dp = g_stats[(s+1)&1] + ((cl*BCL + row)*BPC + q)*2;
            st_f32(&dp[0], v); st_f32(&dp[1], v2);
          }
        }
      }
    }
    __syncthreads();   // all waves' agent stores drained (vmcnt0 at barrier)
    if (tid == 0)
      __hip_atomic_store(&g_flags[cl][q], s+1, __ATOMIC_RELAXED, __HIP_MEMORY_SCOPE_AGENT);
    if (w == 1) {
      for (;;) {
        int v = (l < BPC) ? __hip_atomic_load(&g_flags[cl][l], __ATOMIC_RELAXED,
                                              __HIP_MEMORY_SCOPE_AGENT)
                          : (s+1);
        if (__all(v >= s+1)) break;
        __builtin_amdgcn_s_sleep(1);
      }
    }
    __syncthreads();
    if (lay == 0) xptr += XMS;
  }

  // final LN (t=NT-1, parity 1) + pooled write (lay1 waves own h2loc/A0/A1)
  if (lay == 1) {
    const float* sp = g_stats[1] + sOff;
    GLDC(sts0,sp,0) GLDC(sts1,sp,16) GLDC(sts2,sp,32) GLDC(sts3,sp,48)
    VMF0()
    lnFinish(true);
    float gg = lng[ucol], bb = lnb[ucol];
    #pragma unroll
    for (int r = 0; r < 4; r++) {
      float v = gg*(lastc[r] + (A1[r]-A0[r])*(1.f/NT)) + 2.f*bb;
      g_pool[(cl*BCL + p*16 + lgp*4 + r)*NH + ucol] = v;
    }
  }
}

__global__ __launch_bounds__(256) void proj_kernel(const float* __restrict__ bp,
                                                   float* __restrict__ out) {
  __shared__ float pr[NH];
  int b = blockIdx.x, o = threadIdx.x;
  pr[o] = g_pool[b*NH + o];
  pr[o+256] = g_pool[b*NH + 256 + o];
  __syncthreads();
  float acc = bp[o];
  #pragma unroll 8
  for (int u = 0; u < NH; ++u) acc = fmaf(pr[u], g_Wt[u*256 + o], acc);
  out[b*256 + o] = 0.5f*acc*(1.f + erff(acc*0.70710678118654752f));
}

extern "C" void kernel_launch(void* const* d_in, const int* in_sizes, int n_in,
                              void* d_out, int out_size, void* d_ws, size_t ws_size,
                              hipStream_t stream) {
  const float* x    = (const float*)d_in[0];
  const int*   mask = (const int*)d_in[1];
  const float* Wih0 = (const float*)d_in[2];
  const float* Whh0 = (const float*)d_in[3];
  const float* bih0 = (const float*)d_in[4];
  const float* bhh0 = (const float*)d_in[5];
  const float* Wih1 = (const float*)d_in[6];
  const float* Whh1 = (const float*)d_in[7];
  const float* bih1 = (const float*)d_in[8];
  const float* bhh1 = (const float*)d_in[9];
  const float* lng  = (const float*)d_in[10];
  const float* lnb  = (const float*)d_in[11];
  const float* Wp   = (const float*)d_in[12];
  const float* bp   = (const float*)d_in[13];
  float* out = (float*)d_out;
  (void)in_sizes; (void)n_in; (void)out_size; (void)d_ws; (void)ws_size;

  hipFuncSetAttribute(reinterpret_cast<const void*>(gru_main),
                      hipFuncAttributeMaxDynamicSharedMemorySize, 162816);

  hipLaunchKernelGGL(init_kernel, dim3(2048), dim3(256), 0, stream, Wp, x, mask);
  hipLaunchKernelGGL(gru_main, dim3(256), dim3(256), 162816, stream,
                     Wih0, Whh0, bih0, bhh0, Wih1, Whh1, bih1, bhh1, lng, lnb);
  hipLaunchKernelGGL(proj_kernel, dim3(NB), dim3(256), 0, stream, bp, out);
}